// Round 5
// baseline (515.020 us; speedup 1.0000x reference)
//
#include <hip/hip_runtime.h>
#include <stdint.h>

#define NHEADS 8
#define NTOK   3137
#define BATCH  16
#define CDIM   512
#define MT     (BATCH*NTOK)   // 50192

typedef unsigned short u16;
typedef float f32x4  __attribute__((ext_vector_type(4)));
typedef short bf16x8 __attribute__((ext_vector_type(8)));

__device__ __forceinline__ float bf2f(u16 u){
  union { uint32_t i; float f; } x; x.i = ((uint32_t)u) << 16; return x.f;
}
__device__ __forceinline__ u16 f2bf(float f){
  union { float f; uint32_t i; } x; x.f = f;
  uint32_t r = x.i + 0x7fffu + ((x.i >> 16) & 1u);
  return (u16)(r >> 16);
}
__device__ __forceinline__ void async_ld16(void* lds, const void* g){
  __builtin_amdgcn_global_load_lds((const __attribute__((address_space(1))) void*)g,
                                   (__attribute__((address_space(3))) void*)lds, 16, 0, 0);
}
#define BARM()   asm volatile("s_barrier" ::: "memory")
#define WAITV(N) asm volatile("s_waitcnt vmcnt(" #N ")" ::: "memory")
#define MFMA16(d,a,b) d = __builtin_amdgcn_mfma_f32_16x16x32_bf16(a,b,d,0,0,0)

// ---------------- K0: fp32 -> bf16 cast ----------------
__global__ void cvt_kernel(const float* __restrict__ src, u16* __restrict__ dst, int n4){
  int i = blockIdx.x * blockDim.x + threadIdx.x;
  if (i < n4){
    float4 v = ((const float4*)src)[i];
    uint32_t lo = ((uint32_t)f2bf(v.y) << 16) | f2bf(v.x);
    uint32_t hi = ((uint32_t)f2bf(v.w) << 16) | f2bf(v.z);
    ((uint2*)dst)[i] = make_uint2(lo, hi);
  }
}

// ---------------- GEMM: m201-faithful 8-phase counted-vmcnt schedule ----------------
// C[m][o] = sum_k A[m][k]*Bw[o][k] + bias[o], K=512, BK=64, 256x256 tile, 8 waves (2Mx4N).
// Each half-tile (A0/A1/B0/B1, 128x64) is ds_read ONCE per K-tile into retained regs:
//   Q1 reads A0,B0; Q2 reads A1 (B0 from regs); Q3 reads B1 (A0 from regs); Q4 regs only.
// Stage slots (1 half-tile = 2 loads/thread per phase), tiles T=2i (buf0), T+1 (buf1):
//   p1:B1(T+1)  p2:B0(T+2)  p3:A0(T+2)  p4:A1(T+2)+vmcnt(6)
//   p5:B1(T+2)  p6:B0(T+3)  p7:A0(T+3)  p8:A1(T+3)+vmcnt(6)
// Every read is covered by the preceding vmcnt(6) (3 half-tiles in flight); every
// overwrite lands in a region whose last reader's barrier has passed. Raw s_barrier only.
// MODE 0: scatter bf16 to q/k/v [b*8+h][n][64].  MODE 1: fp32 out [m][512].
template<int MODE>
__global__ __launch_bounds__(512, 1) void gemm8(
    const u16* __restrict__ A, const u16* __restrict__ Bw, const float* __restrict__ bias,
    u16* __restrict__ q_s, u16* __restrict__ k_s, u16* __restrict__ v_s,
    float* __restrict__ outF, int M)
{
  __shared__ __align__(16) u16 smem[65536];   // 128 KiB: buf{0,1} x {A0,A1,B0,B1} x 8192
  const int t = threadIdx.x;
  const int w = t >> 6, l = t & 63;
  const int wr = w >> 2, wc = w & 3;          // 2 x 4 waves
  const int lr = l & 15, lg = l >> 4;

  // T1: bijective XCD-aware remap (m204)
  const int nx = gridDim.x;
  const int nwg = nx * gridDim.y;
  const int orig = blockIdx.y * nx + blockIdx.x;
  const int q8 = nwg >> 3, r8 = nwg & 7;
  const int xcd = orig & 7;
  const int wgid = (xcd < r8 ? xcd*(q8+1) : r8*(q8+1) + (xcd-r8)*q8) + (orig >> 3);
  const int n0 = (wgid % nx) * 256;
  const int m0 = (wgid / nx) * 256;

  f32x4 acc[8][4];
#pragma unroll
  for (int i=0;i<8;i++)
#pragma unroll
    for (int j=0;j<4;j++) acc[i][j] = (f32x4){0.f,0.f,0.f,0.f};

  // stage one 128x64 half-tile. region: 0=A0 1=A1 2=B0 3=B1
  auto stageH = [&](int buf, int region, int tile){
    u16* dst = smem + buf*32768 + region*8192;
    const int k0 = tile*64;
#pragma unroll
    for (int j=0;j<2;j++){
      int qc = t + 512*j;                 // R=row(0..127), c=chunk(0..7)
      int R = qc >> 3, c = qc & 7;
      int cs = (c ^ (R & 7)) * 8;         // pre-swizzled global source (rule #21)
      if (region < 2){
        int ar = m0 + region*128 + R; if (ar > M-1) ar = M-1;
        async_ld16(&dst[qc*8], &A[(size_t)ar*512 + k0 + cs]);
      } else {
        int br = n0 + (region-2)*128 + R;
        async_ld16(&dst[qc*8], &Bw[(size_t)br*512 + k0 + cs]);
      }
    }
  };
  auto rdA = [&](int buf, int rh, int f, int ks)->bf16x8 {
    int row = wr*64 + f*16 + lr;
    int chunk = ks*4 + lg;
    return *(const bf16x8*)&smem[buf*32768 + rh*8192 + row*64 + ((chunk ^ (row&7))*8)];
  };
  auto rdB = [&](int buf, int ch, int g, int ks)->bf16x8 {
    int col = wc*32 + g*16 + lr;
    int chunk = ks*4 + lg;
    return *(const bf16x8*)&smem[buf*32768 + 16384 + ch*8192 + col*64 + ((chunk ^ (col&7))*8)];
  };

  // prologue: tile0 all 4 halves + tile1's B0,A0,A1  (oldest-first)
  stageH(0,2,0); stageH(0,0,0); stageH(0,1,0); stageH(0,3,0);
  stageH(1,2,1); stageH(1,0,1); stageH(1,1,1);
  WAITV(6);            // tile0's 4 halves (8 loads) landed
  BARM();

  bf16x8 a0f[4][2], a1f[4][2], bf[2][2];

  for (int i = 0; i < 4; ++i){
    const int T = 2*i;
    const bool st = (i < 3);
    // ---- p1 = Q1(T): read A0,B0(buf0) ----
#pragma unroll
    for (int f=0; f<4; f++)
#pragma unroll
      for (int ks=0; ks<2; ks++) a0f[f][ks] = rdA(0, 0, f, ks);
#pragma unroll
    for (int g=0; g<2; g++)
#pragma unroll
      for (int ks=0; ks<2; ks++) bf[g][ks] = rdB(0, 0, g, ks);
    stageH(1, 3, T+1);                           // B1(T+1)
    BARM();
    __builtin_amdgcn_s_setprio(1);
#pragma unroll
    for (int ks=0; ks<2; ks++)
#pragma unroll
      for (int f=0; f<4; f++)
#pragma unroll
        for (int g=0; g<2; g++) MFMA16(acc[f][g], a0f[f][ks], bf[g][ks]);
    __builtin_amdgcn_s_setprio(0);
    BARM();
    // ---- p2 = Q2(T): read A1 ----
#pragma unroll
    for (int f=0; f<4; f++)
#pragma unroll
      for (int ks=0; ks<2; ks++) a1f[f][ks] = rdA(0, 1, f, ks);
    if (st) stageH(0, 2, T+2);                   // B0(T+2)
    BARM();
    __builtin_amdgcn_s_setprio(1);
#pragma unroll
    for (int ks=0; ks<2; ks++)
#pragma unroll
      for (int f=0; f<4; f++)
#pragma unroll
        for (int g=0; g<2; g++) MFMA16(acc[4+f][g], a1f[f][ks], bf[g][ks]);
    __builtin_amdgcn_s_setprio(0);
    BARM();
    // ---- p3 = Q3(T): read B1 ----
#pragma unroll
    for (int g=0; g<2; g++)
#pragma unroll
      for (int ks=0; ks<2; ks++) bf[g][ks] = rdB(0, 1, g, ks);
    if (st) stageH(0, 0, T+2);                   // A0(T+2)
    BARM();
    __builtin_amdgcn_s_setprio(1);
#pragma unroll
    for (int ks=0; ks<2; ks++)
#pragma unroll
      for (int f=0; f<4; f++)
#pragma unroll
        for (int g=0; g<2; g++) MFMA16(acc[f][2+g], a0f[f][ks], bf[g][ks]);
    __builtin_amdgcn_s_setprio(0);
    BARM();
    // ---- p4 = Q4(T): regs only ----
    if (st) stageH(0, 1, T+2);                   // A1(T+2)
    if (st) { WAITV(6); } else { WAITV(0); }
    BARM();
    __builtin_amdgcn_s_setprio(1);
#pragma unroll
    for (int ks=0; ks<2; ks++)
#pragma unroll
      for (int f=0; f<4; f++)
#pragma unroll
        for (int g=0; g<2; g++) MFMA16(acc[4+f][2+g], a1f[f][ks], bf[g][ks]);
    __builtin_amdgcn_s_setprio(0);
    BARM();
    // ---- p5 = Q1(T+1): read A0,B0(buf1) ----
#pragma unroll
    for (int f=0; f<4; f++)
#pragma unroll
      for (int ks=0; ks<2; ks++) a0f[f][ks] = rdA(1, 0, f, ks);
#pragma unroll
    for (int g=0; g<2; g++)
#pragma unroll
      for (int ks=0; ks<2; ks++) bf[g][ks] = rdB(1, 0, g, ks);
    if (st) stageH(0, 3, T+2);                   // B1(T+2)
    BARM();
    __builtin_amdgcn_s_setprio(1);
#pragma unroll
    for (int ks=0; ks<2; ks++)
#pragma unroll
      for (int f=0; f<4; f++)
#pragma unroll
        for (int g=0; g<2; g++) MFMA16(acc[f][g], a0f[f][ks], bf[g][ks]);
    __builtin_amdgcn_s_setprio(0);
    BARM();
    // ---- p6 = Q2(T+1): read A1 ----
#pragma unroll
    for (int f=0; f<4; f++)
#pragma unroll
      for (int ks=0; ks<2; ks++) a1f[f][ks] = rdA(1, 1, f, ks);
    if (st) stageH(1, 2, T+3);                   // B0(T+3)
    BARM();
    __builtin_amdgcn_s_setprio(1);
#pragma unroll
    for (int ks=0; ks<2; ks++)
#pragma unroll
      for (int f=0; f<4; f++)
#pragma unroll
        for (int g=0; g<2; g++) MFMA16(acc[4+f][g], a1f[f][ks], bf[g][ks]);
    __builtin_amdgcn_s_setprio(0);
    BARM();
    // ---- p7 = Q3(T+1): read B1 ----
#pragma unroll
    for (int g=0; g<2; g++)
#pragma unroll
      for (int ks=0; ks<2; ks++) bf[g][ks] = rdB(1, 1, g, ks);
    if (st) stageH(1, 0, T+3);                   // A0(T+3)
    BARM();
    __builtin_amdgcn_s_setprio(1);
#pragma unroll
    for (int ks=0; ks<2; ks++)
#pragma unroll
      for (int f=0; f<4; f++)
#pragma unroll
        for (int g=0; g<2; g++) MFMA16(acc[f][2+g], a0f[f][ks], bf[g][ks]);
    __builtin_amdgcn_s_setprio(0);
    BARM();
    // ---- p8 = Q4(T+1): regs only ----
    if (st) stageH(1, 1, T+3);                   // A1(T+3)
    if (st) { WAITV(6); }
    BARM();
    __builtin_amdgcn_s_setprio(1);
#pragma unroll
    for (int ks=0; ks<2; ks++)
#pragma unroll
      for (int f=0; f<4; f++)
#pragma unroll
        for (int g=0; g<2; g++) MFMA16(acc[4+f][2+g], a1f[f][ks], bf[g][ks]);
    __builtin_amdgcn_s_setprio(0);
    BARM();
  }

  // ---------------- epilogue (validated in round 3): LDS restage, coalesced write ----------------
  float bv[2][2];
#pragma unroll
  for (int nh=0; nh<2; nh++)
#pragma unroll
    for (int g=0; g<2; g++)
      bv[nh][g] = bias[n0 + nh*128 + wc*32 + g*16 + lr];

  if (MODE == 0){
    u16* wa = smem;   // logical [256][256] bf16, chunk-XOR swizzled
#pragma unroll
    for (int mh=0; mh<2; mh++)
#pragma unroll
      for (int f=0; f<4; f++)
#pragma unroll
        for (int nh=0; nh<2; nh++)
#pragma unroll
          for (int g=0; g<2; g++)
#pragma unroll
            for (int r=0; r<4; r++){
              int rl = mh*128 + wr*64 + f*16 + lg*4 + r;
              int cl = nh*128 + wc*32 + g*16 + lr;
              wa[rl*256 + (((cl>>3) ^ (rl&31))<<3) + (cl&7)] =
                  f2bf(acc[mh*4+f][nh*2+g][r] + bv[nh][g]);
            }
    BARM();
#pragma unroll
    for (int i=0; i<16; i++){
      int tau = t + 512*i;
      int rl = tau >> 5, ch = tau & 31;
      int m = m0 + rl;
      if (m < M){
        uint4 val = *(const uint4*)&wa[rl*256 + ((ch ^ (rl&31))<<3)];
        int o = n0 + ch*8;
        int part = o >> 9, hq = (o>>6)&7, d = o&63;
        int bb2 = m / NTOK, n = m - bb2*NTOK;
        u16* dst = (part==0) ? q_s : ((part==1) ? k_s : v_s);
        *(uint4*)&dst[((size_t)(bb2*8+hq)*NTOK + n)*64 + d] = val;
      }
    }
  } else {
    float* wf = (float*)smem;  // logical [128][256] f32 per pass
#pragma unroll
    for (int mh=0; mh<2; mh++){
      BARM();
#pragma unroll
      for (int f=0; f<4; f++)
#pragma unroll
        for (int nh=0; nh<2; nh++)
#pragma unroll
          for (int g=0; g<2; g++)
#pragma unroll
            for (int r=0; r<4; r++){
              int rl = wr*64 + f*16 + lg*4 + r;
              int cl = nh*128 + wc*32 + g*16 + lr;
              wf[rl*256 + (((cl>>2) ^ ((rl&31)<<1))<<2) + (cl&3)] =
                  acc[mh*4+f][nh*2+g][r] + bv[nh][g];
            }
      BARM();
#pragma unroll
      for (int i=0; i<16; i++){
        int tau = t + 512*i;
        int rl = tau >> 6, ch = tau & 63;
        int m = m0 + mh*128 + rl;
        if (m < M){
          float4 val = *(const float4*)&wf[rl*256 + ((ch ^ ((rl&31)<<1))<<2)];
          *(float4*)&outF[(size_t)m*512 + n0 + ch*4] = val;
        }
      }
    }
  }
}

// ---------------- K2: partial kv = exp(k)^T @ v, column sums of exp(k); 4-way n-split ----------------
__global__ __launch_bounds__(256) void kv_partial(
    const u16* __restrict__ k_s, const u16* __restrict__ v_s,
    float* __restrict__ kv_p, float* __restrict__ s_p)
{
  __shared__ float smem[18432];
  const int t  = threadIdx.x;
  const int bh = blockIdx.x;
  const int hf = blockIdx.y;            // 0..3
  const size_t base = (size_t)bh * NTOK * 64;
  const int srow = t >> 3;
  const int scol = (t & 7) * 8;
  const int ns = t >> 6;
  const int kg = (t >> 3) & 7;
  const int dg = t & 7;

  float accv[8][8];
#pragma unroll
  for (int a=0;a<8;a++)
#pragma unroll
    for (int c=0;c<8;c++) accv[a][c] = 0.f;
  float s_loc[8];
#pragma unroll
  for (int i=0;i<8;i++) s_loc[i] = 0.f;

  float* ek = smem;
  float* vv = smem + 2048;
  const int n_beg = hf * 800;
  const int n_end = (hf == 3) ? NTOK : (n_beg + 800);

  for (int n0 = n_beg; n0 < n_end; n0 += 32){
    __syncthreads();
    int n = n0 + srow;
    float et[8], vf[8];
    if (n < n_end){
      uint4 kvec = *(const uint4*)&k_s[base + (size_t)n*64 + scol];
      uint4 vvec = *(const uint4*)&v_s[base + (size_t)n*64 + scol];
      const u16* kp = (const u16*)&kvec;
      const u16* vp = (const u16*)&vvec;
#pragma unroll
      for (int i=0;i<8;i++){
        et[i] = __expf(bf2f(kp[i]));
        s_loc[i] += et[i];
        vf[i] = bf2f(vp[i]);
      }
    } else {
#pragma unroll
      for (int i=0;i<8;i++){ et[i]=0.f; vf[i]=0.f; }
    }
    *(float4*)&ek[srow*64 + scol]     = make_float4(et[0],et[1],et[2],et[3]);
    *(float4*)&ek[srow*64 + scol + 4] = make_float4(et[4],et[5],et[6],et[7]);
    *(float4*)&vv[srow*64 + scol]     = make_float4(vf[0],vf[1],vf[2],vf[3]);
    *(float4*)&vv[srow*64 + scol + 4] = make_float4(vf[4],vf[5],vf[6],vf[7]);
    __syncthreads();
#pragma unroll
    for (int i=0;i<8;i++){
      int nl = ns + 4*i;
      float4 e0 = *(const float4*)&ek[nl*64 + kg*8];
      float4 e1 = *(const float4*)&ek[nl*64 + kg*8 + 4];
      float4 v0 = *(const float4*)&vv[nl*64 + dg*8];
      float4 v1 = *(const float4*)&vv[nl*64 + dg*8 + 4];
      float ea[8] = {e0.x,e0.y,e0.z,e0.w,e1.x,e1.y,e1.z,e1.w};
      float va[8] = {v0.x,v0.y,v0.z,v0.w,v1.x,v1.y,v1.z,v1.w};
#pragma unroll
      for (int a=0;a<8;a++)
#pragma unroll
        for (int c=0;c<8;c++) accv[a][c] += ea[a]*va[c];
    }
  }
  __syncthreads();
  float* part_kv = smem;
  float* part_s  = smem + 16384;
#pragma unroll
  for (int a=0;a<8;a++)
#pragma unroll
    for (int c=0;c<8;c++)
      part_kv[(size_t)ns*4096 + (kg*8+a)*64 + dg*8+c] = accv[a][c];
#pragma unroll
  for (int i=0;i<8;i++) part_s[srow*64 + scol + i] = s_loc[i];
  __syncthreads();
  const size_t obase = ((size_t)hf*128 + bh) * 4096;
  for (int i=0;i<16;i++){
    int e = t*16 + i;
    kv_p[obase + e] = part_kv[e] + part_kv[4096+e] + part_kv[8192+e] + part_kv[12288+e];
  }
  if (t < 64){
    float s = 0.f;
    for (int r=0;r<32;r++) s += part_s[r*64 + t];
    s_p[((size_t)hf*128 + bh)*64 + t] = s;
  }
}

// ---------------- K2b: combine quarters, divide by S, write kv^T bf16 [bh][d][k] ----------------
__global__ void kv_reduce(const float* __restrict__ kv_p, const float* __restrict__ s_p,
                          u16* __restrict__ kvT){
  const int bh = blockIdx.x, t = threadIdx.x;
  for (int i=0;i<16;i++){
    int e = t*16 + i;
    int k = e >> 6, d = e & 63;
    float v = 0.f, S = 0.f;
#pragma unroll
    for (int hf=0; hf<4; hf++){
      v += kv_p[(size_t)(hf*128 + bh)*4096 + e];
      S += s_p[(hf*128 + bh)*64 + k];
    }
    kvT[(size_t)bh*4096 + d*64 + k] = f2bf(v / S);
  }
}

// ---------------- K3: fused depthwise conv + factor_att for one (b,h,y) row ----------------
template<int R>
__global__ __launch_bounds__(256) void conv_fa(
    const u16* __restrict__ v_s, const u16* __restrict__ q_s,
    const u16* __restrict__ kvT,
    const float* __restrict__ wsrc, const float* __restrict__ bsrc,
    int h0, u16* __restrict__ out_pre)
{
  constexpr int KK = 2*R + 1;
  constexpr int TAPS = KK*KK;
  __shared__ __align__(16) u16 smem[8192 + KK*3584];   // [0,8192)u16: sQ|sKV, later fa f32
  u16* vt = smem + 8192;
  const int t = threadIdx.x;
  const int y  = blockIdx.x;
  const int hh = blockIdx.y;
  const int b  = blockIdx.z;
  const int h  = h0 + hh;
  const int bh = b*8 + h;
  const size_t base = (size_t)bh * NTOK * 64;
  const int n0 = 1 + y*56;

#pragma unroll
  for (int j=0;j<2;j++){
    int qq = t + 256*j;
    int row = qq >> 3, c = qq & 7;
    int cs = (c ^ (row & 7)) * 8;
    int n = n0 + row; if (n > NTOK-1) n = NTOK-1;
    async_ld16(&smem[qq*8], &q_s[base + (size_t)n*64 + cs]);
    async_ld16(&smem[4096 + qq*8], &kvT[(size_t)bh*4096 + row*64 + cs]);
  }
  for (int ry=0; ry<KK; ry++){
    int yy = y - R + ry;
    for (int idx = t; idx < 448; idx += 256){
      uint4 val = make_uint4(0u,0u,0u,0u);
      if (yy >= 0 && yy < 56)
        val = *(const uint4*)&v_s[base + (size_t)(1 + yy*56)*64 + idx*8];
      *(uint4*)&vt[ry*3584 + idx*8] = val;
    }
  }
  __syncthreads();

  const int w = t >> 6, l = t & 63;
  const int lr = l & 15, lg = l >> 4;
  f32x4 fac[4];
#pragma unroll
  for (int j=0;j<4;j++) fac[j] = (f32x4){0.f,0.f,0.f,0.f};
#pragma unroll
  for (int ks=0; ks<2; ks++){
    int chunk = ks*4 + lg;
    int arow = w*16 + lr;
    bf16x8 af = *(const bf16x8*)&smem[arow*64 + ((chunk ^ (arow & 7))*8)];
#pragma unroll
    for (int fj=0; fj<4; fj++){
      int col = fj*16 + lr;
      bf16x8 bvv = *(const bf16x8*)&smem[4096 + col*64 + ((chunk ^ (col & 7))*8)];
      MFMA16(fac[fj], af, bvv);
    }
  }

  const int d = l;
  const int xg = w;
  float wreg[TAPS];
#pragma unroll
  for (int i=0;i<TAPS;i++) wreg[i] = wsrc[(hh*64 + d)*TAPS + i];
  const float bias = bsrc[hh*64 + d];
  float creg[14];
#pragma unroll
  for (int i=0;i<14;i++) creg[i] = bias;
  const int x0 = xg * 14;
#pragma unroll
  for (int ry=0; ry<KK; ry++){
    float rw[14 + 2*R];
#pragma unroll
    for (int i=0; i<14+2*R; i++){
      int xx = x0 - R + i;
      rw[i] = (xx >= 0 && xx < 56) ? bf2f(vt[ry*3584 + xx*64 + d]) : 0.f;
    }
#pragma unroll
    for (int xi=0; xi<14; xi++)
#pragma unroll
      for (int rx=0; rx<KK; rx++)
        creg[xi] += rw[xi+rx] * wreg[ry*KK + rx];
  }

  float qv[14];
#pragma unroll
  for (int xi=0; xi<14; xi++){
    int row = x0 + xi;
    int chunk = d >> 3, e = d & 7;
    qv[xi] = bf2f(smem[row*64 + ((chunk ^ (row & 7))*8) + e]);
  }

  __syncthreads();
  float* fa = (float*)smem;
#pragma unroll
  for (int fj=0; fj<4; fj++)
#pragma unroll
    for (int r=0; r<4; r++)
      fa[(w*16 + lg*4 + r)*64 + fj*16 + lr] = 0.125f * fac[fj][r];
  __syncthreads();

#pragma unroll
  for (int xi=0; xi<14; xi++){
    int nn = n0 + x0 + xi;
    out_pre[((size_t)b*NTOK + nn)*CDIM + h*64 + d] =
        f2bf(fa[(x0 + xi)*64 + d] + creg[xi]*qv[xi]);
  }
}

// ---------------- K4: n=0 row: out = scale * q[0] @ kvT^T ----------------
__global__ void fa0_kernel(const u16* __restrict__ q_s, const u16* __restrict__ kvT,
                           u16* __restrict__ out_pre){
  const int b = blockIdx.x, t = threadIdx.x;   // 512 threads
  const int h = t >> 6, d = t & 63;
  const int bh = b*8 + h;
  float s = 0.f;
#pragma unroll
  for (int k=0; k<64; k++)
    s += bf2f(q_s[(size_t)bh*NTOK*64 + k]) * bf2f(kvT[(size_t)bh*4096 + d*64 + k]);
  out_pre[(size_t)b*NTOK*CDIM + h*64 + d] = f2bf(0.125f * s);
}

extern "C" void kernel_launch(void* const* d_in, const int* in_sizes, int n_in,
                              void* d_out, int out_size, void* d_ws, size_t ws_size,
                              hipStream_t stream)
{
  const float* x      = (const float*)d_in[0];
  const float* qkv_w  = (const float*)d_in[1];
  const float* qkv_b  = (const float*)d_in[2];
  const float* proj_w = (const float*)d_in[3];
  const float* proj_b = (const float*)d_in[4];
  const float* w3 = (const float*)d_in[5];
  const float* b3 = (const float*)d_in[6];
  const float* w5 = (const float*)d_in[7];
  const float* b5 = (const float*)d_in[8];
  const float* w7 = (const float*)d_in[9];
  const float* b7 = (const float*)d_in[10];
  float* out = (float*)d_out;

  char* ws = (char*)d_ws;
  size_t off = 0;
  auto alloc = [&](size_t bytes) -> void* {
    void* p = ws + off;
    off += (bytes + 255) & ~(size_t)255;
    return p;
  };
  u16*   x_bf     = (u16*)alloc((size_t)MT*512*2);        // reused as out_pre after qkv GEMM
  u16*   qkvw_bf  = (u16*)alloc((size_t)1536*512*2);
  u16*   projw_bf = (u16*)alloc((size_t)512*512*2);
  u16*   q_s      = (u16*)alloc((size_t)128*NTOK*64*2);
  u16*   k_s      = (u16*)alloc((size_t)128*NTOK*64*2);
  u16*   v_s      = (u16*)alloc((size_t)128*NTOK*64*2);
  u16*   kvT      = (u16*)alloc((size_t)128*4096*2);
  float* kv_p     = (float*)alloc((size_t)4*128*4096*4);
  float* s_p      = (float*)alloc((size_t)4*128*64*4);
  u16*   out_pre  = x_bf;

  { int n4 = (MT*512)/4;   cvt_kernel<<<(n4+255)/256, 256, 0, stream>>>(x, x_bf, n4); }
  { int n4 = (1536*512)/4; cvt_kernel<<<(n4+255)/256, 256, 0, stream>>>(qkv_w, qkvw_bf, n4); }
  { int n4 = (512*512)/4;  cvt_kernel<<<(n4+255)/256, 256, 0, stream>>>(proj_w, projw_bf, n4); }

  // qkv: M=50192, N=1536, K=512 — 8-phase 256x256
  gemm8<0><<<dim3(6, 197), 512, 0, stream>>>(x_bf, qkvw_bf, qkv_b, q_s, k_s, v_s, nullptr, MT);

  kv_partial<<<dim3(128, 4), 256, 0, stream>>>(k_s, v_s, kv_p, s_p);
  kv_reduce<<<128, 256, 0, stream>>>(kv_p, s_p, kvT);
  fa0_kernel<<<16, 512, 0, stream>>>(q_s, kvT, out_pre);

  conv_fa<1><<<dim3(56, 2, 16), 256, 0, stream>>>(v_s, q_s, kvT, w3, b3, 0, out_pre);
  conv_fa<2><<<dim3(56, 3, 16), 256, 0, stream>>>(v_s, q_s, kvT, w5, b5, 2, out_pre);
  conv_fa<3><<<dim3(56, 3, 16), 256, 0, stream>>>(v_s, q_s, kvT, w7, b7, 5, out_pre);

  // proj: M=50192, N=512, K=512 — 8-phase 256x256, fp32 out
  gemm8<1><<<dim3(2, 197), 512, 0, stream>>>(out_pre, projw_bf, proj_b, nullptr, nullptr, nullptr, out, MT);
}

// Round 6
// 383.924 us; speedup vs baseline: 1.3415x; 1.3415x over previous
//
#include <hip/hip_runtime.h>
#include <stdint.h>

#define NHEADS 8
#define NTOK   3137
#define BATCH  16
#define CDIM   512
#define MT     (BATCH*NTOK)   // 50192

typedef unsigned short u16;
typedef float f32x4  __attribute__((ext_vector_type(4)));
typedef short bf16x8 __attribute__((ext_vector_type(8)));

__device__ __forceinline__ float bf2f(u16 u){
  union { uint32_t i; float f; } x; x.i = ((uint32_t)u) << 16; return x.f;
}
__device__ __forceinline__ u16 f2bf(float f){
  union { float f; uint32_t i; } x; x.f = f;
  uint32_t r = x.i + 0x7fffu + ((x.i >> 16) & 1u);
  return (u16)(r >> 16);
}
__device__ __forceinline__ void async_ld16(void* lds, const void* g){
  __builtin_amdgcn_global_load_lds((const __attribute__((address_space(1))) void*)g,
                                   (__attribute__((address_space(3))) void*)lds, 16, 0, 0);
}
#define BARM()   asm volatile("s_barrier" ::: "memory")
#define WAITV(N) asm volatile("s_waitcnt vmcnt(" #N ")" ::: "memory")
#define MFMA16(d,a,b) d = __builtin_amdgcn_mfma_f32_16x16x32_bf16(a,b,d,0,0,0)

// ---------------- K0: fp32 -> bf16 cast ----------------
__global__ void cvt_kernel(const float* __restrict__ src, u16* __restrict__ dst, int n4){
  int i = blockIdx.x * blockDim.x + threadIdx.x;
  if (i < n4){
    float4 v = ((const float4*)src)[i];
    uint32_t lo = ((uint32_t)f2bf(v.y) << 16) | f2bf(v.x);
    uint32_t hi = ((uint32_t)f2bf(v.w) << 16) | f2bf(v.z);
    ((uint2*)dst)[i] = make_uint2(lo, hi);
  }
}

// ---------------- GEMM: 2-phase double-buffer + COUNTED vmcnt (T4-min) ----------------
// C[m][o] = sum_k A[m][k]*Bw[o][k] + bias[o], K=512, BK=64.
// Loop: stage(next) -> s_waitcnt vmcnt(8) [cur's 8 per-wave loads landed; next's fly]
//       -> s_barrier -> MFMA(cur) -> s_barrier.  Next-tile loads stay in flight across
// both barriers (never vmcnt(0) in steady state). Overwrite safety: stage(t+1) is
// ISSUED after the barrier that ends compute(t-1)'s reads of that buffer.
// Per-wave instrs/stage = (BM*8 + BN*8)/THREADS = 8 for both configs used here.
// MODE 0: scatter bf16 to q/k/v [b*8+h][n][64].  MODE 1: fp32 out [m][512].
template<int BM,int BN,int WM,int WN,int MODE>
__global__ __launch_bounds__(WM*WN*64, 2) void gemm2(
    const u16* __restrict__ A, const u16* __restrict__ Bw, const float* __restrict__ bias,
    u16* __restrict__ q_s, u16* __restrict__ k_s, u16* __restrict__ v_s,
    float* __restrict__ outF, int M)
{
  constexpr int THREADS = WM*WN*64;
  constexpr int MF = BM/(WM*16);
  constexpr int NF = BN/(WN*16);
  constexpr int WROWS = BM/WM;
  constexpr int WCOLS = BN/WN;
  static_assert((BM*8)/THREADS + (BN*8)/THREADS == 8, "vmcnt literal assumes 8 loads/stage");
  __shared__ __align__(16) u16 smem[2*(BM+BN)*64];

  const int t = threadIdx.x;
  const int w = t >> 6, l = t & 63;
  const int wr = w / WN, wc = w % WN;
  const int lr = l & 15, lg = l >> 4;

  const int nx = gridDim.x;
  const int nwg = nx * gridDim.y;
  const int orig = blockIdx.y * nx + blockIdx.x;
  const int q8 = nwg >> 3, r8 = nwg & 7;
  const int xcd = orig & 7;
  const int wgid = (xcd < r8 ? xcd*(q8+1) : r8*(q8+1) + (xcd-r8)*q8) + (orig >> 3);
  const int n0 = (wgid % nx) * BN;
  const int m0 = (wgid / nx) * BM;

  f32x4 acc[MF][NF];
#pragma unroll
  for (int i=0;i<MF;i++)
#pragma unroll
    for (int j=0;j<NF;j++) acc[i][j] = (f32x4){0.f,0.f,0.f,0.f};

  auto stage = [&](int bi, int k0){
    u16* da = smem + bi*(BM*64);
    u16* db = smem + 2*BM*64 + bi*(BN*64);
#pragma unroll
    for (int j=0;j<(BM*8)/THREADS;j++){
      int qc = t + THREADS*j;
      int R = qc >> 3, c = qc & 7;
      int cs = (c ^ (R & 7)) * 8;
      int ar = m0 + R; if (ar > M-1) ar = M-1;
      async_ld16(&da[qc*8], &A[(size_t)ar*512 + k0 + cs]);
    }
#pragma unroll
    for (int j=0;j<(BN*8)/THREADS;j++){
      int qc = t + THREADS*j;
      int R = qc >> 3, c = qc & 7;
      int cs = (c ^ (R & 7)) * 8;
      async_ld16(&db[qc*8], &Bw[(size_t)(n0+R)*512 + k0 + cs]);
    }
  };

  stage(0, 0);
  int cur = 0;
  for (int kt = 0; kt < 8; ++kt){
    if (kt < 7) stage(cur ^ 1, (kt+1)*64);
    if (kt < 7) { WAITV(8); } else { WAITV(0); }   // cur's loads landed; next's fly
    BARM();                                         // all waves' shares landed
    const u16* a_base = smem + cur*(BM*64);
    const u16* b_base = smem + 2*BM*64 + cur*(BN*64);
    __builtin_amdgcn_s_setprio(1);
#pragma unroll
    for (int ks=0; ks<2; ks++){
      bf16x8 af[MF], bfv[NF];
      int chunk = ks*4 + lg;
#pragma unroll
      for (int fi=0;fi<MF;fi++){
        int row = wr*WROWS + fi*16 + lr;
        af[fi] = *(const bf16x8*)&a_base[row*64 + ((chunk ^ (row & 7))*8)];
      }
#pragma unroll
      for (int fj=0;fj<NF;fj++){
        int col = wc*WCOLS + fj*16 + lr;
        bfv[fj] = *(const bf16x8*)&b_base[col*64 + ((chunk ^ (col & 7))*8)];
      }
#pragma unroll
      for (int fi=0;fi<MF;fi++)
#pragma unroll
        for (int fj=0;fj<NF;fj++)
          acc[fi][fj] = __builtin_amdgcn_mfma_f32_16x16x32_bf16(af[fi], bfv[fj], acc[fi][fj], 0, 0, 0);
    }
    __builtin_amdgcn_s_setprio(0);
    BARM();                                         // reads of buf[cur] done -> reusable
    cur ^= 1;
  }

  if (MODE == 0){
    u16* warea = smem + w * (WROWS*WCOLS);
    float bvv[NF];
#pragma unroll
    for (int fj=0;fj<NF;fj++) bvv[fj] = bias[n0 + wc*WCOLS + fj*16 + lr];
#pragma unroll
    for (int fi=0;fi<MF;fi++)
#pragma unroll
      for (int fj=0;fj<NF;fj++)
#pragma unroll
        for (int r=0;r<4;r++)
          warea[(fi*16 + lg*4 + r)*WCOLS + fj*16 + lr] = f2bf(acc[fi][fj][r] + bvv[fj]);
    __syncthreads();
    const int colo = n0 + wc*WCOLS;
    const int part = colo >> 9;
    const int hq   = (colo >> 6) & 7;
    u16* dst = (part == 0) ? q_s : ((part == 1) ? k_s : v_s);
    const int rsub = l >> 3;
    const int csub = (l & 7) * 8;
#pragma unroll
    for (int pass=0; pass<WROWS/8; ++pass){
      int rl = pass*8 + rsub;
      int m = m0 + wr*WROWS + rl;
      if (m < M){
        int bb = m / NTOK;
        int n  = m - bb*NTOK;
        uint4 vv = *(const uint4*)&warea[rl*WCOLS + csub];
        *(uint4*)&dst[((size_t)(bb*8 + hq)*NTOK + n)*64 + csub] = vv;
      }
    }
  } else {
    float* warea = (float*)smem + w * (WROWS*WCOLS);
    float bvv[NF];
#pragma unroll
    for (int fj=0;fj<NF;fj++) bvv[fj] = bias[n0 + wc*WCOLS + fj*16 + lr];
#pragma unroll
    for (int fi=0;fi<MF;fi++)
#pragma unroll
      for (int fj=0;fj<NF;fj++)
#pragma unroll
        for (int r=0;r<4;r++)
          warea[(fi*16 + lg*4 + r)*WCOLS + fj*16 + lr] = acc[fi][fj][r] + bvv[fj];
    __syncthreads();
    const int colo = n0 + wc*WCOLS;
    const int rsub = l >> 4;
    const int csub = (l & 15) * 4;
#pragma unroll
    for (int pass=0; pass<WROWS/4; ++pass){
      int rl = pass*4 + rsub;
      int m = m0 + wr*WROWS + rl;
      if (m < M){
        float4 vv = *(const float4*)&warea[rl*WCOLS + csub];
        *(float4*)&outF[(size_t)m*512 + colo + csub] = vv;
      }
    }
  }
}

// ---------------- K2: partial kv = exp(k)^T @ v, column sums of exp(k); 4-way n-split ----------------
__global__ __launch_bounds__(256) void kv_partial(
    const u16* __restrict__ k_s, const u16* __restrict__ v_s,
    float* __restrict__ kv_p, float* __restrict__ s_p)
{
  __shared__ float smem[18432];
  const int t  = threadIdx.x;
  const int bh = blockIdx.x;
  const int hf = blockIdx.y;            // 0..3
  const size_t base = (size_t)bh * NTOK * 64;
  const int srow = t >> 3;
  const int scol = (t & 7) * 8;
  const int ns = t >> 6;
  const int kg = (t >> 3) & 7;
  const int dg = t & 7;

  float accv[8][8];
#pragma unroll
  for (int a=0;a<8;a++)
#pragma unroll
    for (int c=0;c<8;c++) accv[a][c] = 0.f;
  float s_loc[8];
#pragma unroll
  for (int i=0;i<8;i++) s_loc[i] = 0.f;

  float* ek = smem;
  float* vv = smem + 2048;
  const int n_beg = hf * 800;
  const int n_end = (hf == 3) ? NTOK : (n_beg + 800);

  for (int n0 = n_beg; n0 < n_end; n0 += 32){
    __syncthreads();
    int n = n0 + srow;
    float et[8], vf[8];
    if (n < n_end){
      uint4 kvec = *(const uint4*)&k_s[base + (size_t)n*64 + scol];
      uint4 vvec = *(const uint4*)&v_s[base + (size_t)n*64 + scol];
      const u16* kp = (const u16*)&kvec;
      const u16* vp = (const u16*)&vvec;
#pragma unroll
      for (int i=0;i<8;i++){
        et[i] = __expf(bf2f(kp[i]));
        s_loc[i] += et[i];
        vf[i] = bf2f(vp[i]);
      }
    } else {
#pragma unroll
      for (int i=0;i<8;i++){ et[i]=0.f; vf[i]=0.f; }
    }
    *(float4*)&ek[srow*64 + scol]     = make_float4(et[0],et[1],et[2],et[3]);
    *(float4*)&ek[srow*64 + scol + 4] = make_float4(et[4],et[5],et[6],et[7]);
    *(float4*)&vv[srow*64 + scol]     = make_float4(vf[0],vf[1],vf[2],vf[3]);
    *(float4*)&vv[srow*64 + scol + 4] = make_float4(vf[4],vf[5],vf[6],vf[7]);
    __syncthreads();
#pragma unroll
    for (int i=0;i<8;i++){
      int nl = ns + 4*i;
      float4 e0 = *(const float4*)&ek[nl*64 + kg*8];
      float4 e1 = *(const float4*)&ek[nl*64 + kg*8 + 4];
      float4 v0 = *(const float4*)&vv[nl*64 + dg*8];
      float4 v1 = *(const float4*)&vv[nl*64 + dg*8 + 4];
      float ea[8] = {e0.x,e0.y,e0.z,e0.w,e1.x,e1.y,e1.z,e1.w};
      float va[8] = {v0.x,v0.y,v0.z,v0.w,v1.x,v1.y,v1.z,v1.w};
#pragma unroll
      for (int a=0;a<8;a++)
#pragma unroll
        for (int c=0;c<8;c++) accv[a][c] += ea[a]*va[c];
    }
  }
  __syncthreads();
  float* part_kv = smem;
  float* part_s  = smem + 16384;
#pragma unroll
  for (int a=0;a<8;a++)
#pragma unroll
    for (int c=0;c<8;c++)
      part_kv[(size_t)ns*4096 + (kg*8+a)*64 + dg*8+c] = accv[a][c];
#pragma unroll
  for (int i=0;i<8;i++) part_s[srow*64 + scol + i] = s_loc[i];
  __syncthreads();
  const size_t obase = ((size_t)hf*128 + bh) * 4096;
  for (int i=0;i<16;i++){
    int e = t*16 + i;
    kv_p[obase + e] = part_kv[e] + part_kv[4096+e] + part_kv[8192+e] + part_kv[12288+e];
  }
  if (t < 64){
    float s = 0.f;
    for (int r=0;r<32;r++) s += part_s[r*64 + t];
    s_p[((size_t)hf*128 + bh)*64 + t] = s;
  }
}

// ---------------- K2b: combine quarters, divide by S, write kv^T bf16 [bh][d][k] ----------------
__global__ void kv_reduce(const float* __restrict__ kv_p, const float* __restrict__ s_p,
                          u16* __restrict__ kvT){
  const int bh = blockIdx.x, t = threadIdx.x;
  for (int i=0;i<16;i++){
    int e = t*16 + i;
    int k = e >> 6, d = e & 63;
    float v = 0.f, S = 0.f;
#pragma unroll
    for (int hf=0; hf<4; hf++){
      v += kv_p[(size_t)(hf*128 + bh)*4096 + e];
      S += s_p[(hf*128 + bh)*64 + k];
    }
    kvT[(size_t)bh*4096 + d*64 + k] = f2bf(v / S);
  }
}

// ---------------- K3: fused depthwise conv + factor_att for one (b,h,y) row ----------------
template<int R>
__global__ __launch_bounds__(256) void conv_fa(
    const u16* __restrict__ v_s, const u16* __restrict__ q_s,
    const u16* __restrict__ kvT,
    const float* __restrict__ wsrc, const float* __restrict__ bsrc,
    int h0, u16* __restrict__ out_pre)
{
  constexpr int KK = 2*R + 1;
  constexpr int TAPS = KK*KK;
  __shared__ __align__(16) u16 smem[8192 + KK*3584];   // [0,8192)u16: sQ|sKV, later fa f32
  u16* vt = smem + 8192;
  const int t = threadIdx.x;
  const int y  = blockIdx.x;
  const int hh = blockIdx.y;
  const int b  = blockIdx.z;
  const int h  = h0 + hh;
  const int bh = b*8 + h;
  const size_t base = (size_t)bh * NTOK * 64;
  const int n0 = 1 + y*56;

#pragma unroll
  for (int j=0;j<2;j++){
    int qq = t + 256*j;
    int row = qq >> 3, c = qq & 7;
    int cs = (c ^ (row & 7)) * 8;
    int n = n0 + row; if (n > NTOK-1) n = NTOK-1;
    async_ld16(&smem[qq*8], &q_s[base + (size_t)n*64 + cs]);
    async_ld16(&smem[4096 + qq*8], &kvT[(size_t)bh*4096 + row*64 + cs]);
  }
  for (int ry=0; ry<KK; ry++){
    int yy = y - R + ry;
    for (int idx = t; idx < 448; idx += 256){
      uint4 val = make_uint4(0u,0u,0u,0u);
      if (yy >= 0 && yy < 56)
        val = *(const uint4*)&v_s[base + (size_t)(1 + yy*56)*64 + idx*8];
      *(uint4*)&vt[ry*3584 + idx*8] = val;
    }
  }
  __syncthreads();

  const int w = t >> 6, l = t & 63;
  const int lr = l & 15, lg = l >> 4;
  f32x4 fac[4];
#pragma unroll
  for (int j=0;j<4;j++) fac[j] = (f32x4){0.f,0.f,0.f,0.f};
#pragma unroll
  for (int ks=0; ks<2; ks++){
    int chunk = ks*4 + lg;
    int arow = w*16 + lr;
    bf16x8 af = *(const bf16x8*)&smem[arow*64 + ((chunk ^ (arow & 7))*8)];
#pragma unroll
    for (int fj=0; fj<4; fj++){
      int col = fj*16 + lr;
      bf16x8 bvv = *(const bf16x8*)&smem[4096 + col*64 + ((chunk ^ (col & 7))*8)];
      MFMA16(fac[fj], af, bvv);
    }
  }

  const int d = l;
  const int xg = w;
  float wreg[TAPS];
#pragma unroll
  for (int i=0;i<TAPS;i++) wreg[i] = wsrc[(hh*64 + d)*TAPS + i];
  const float bias = bsrc[hh*64 + d];
  float creg[14];
#pragma unroll
  for (int i=0;i<14;i++) creg[i] = bias;
  const int x0 = xg * 14;
#pragma unroll
  for (int ry=0; ry<KK; ry++){
    float rw[14 + 2*R];
#pragma unroll
    for (int i=0; i<14+2*R; i++){
      int xx = x0 - R + i;
      rw[i] = (xx >= 0 && xx < 56) ? bf2f(vt[ry*3584 + xx*64 + d]) : 0.f;
    }
#pragma unroll
    for (int xi=0; xi<14; xi++)
#pragma unroll
      for (int rx=0; rx<KK; rx++)
        creg[xi] += rw[xi+rx] * wreg[ry*KK + rx];
  }

  float qv[14];
#pragma unroll
  for (int xi=0; xi<14; xi++){
    int row = x0 + xi;
    int chunk = d >> 3, e = d & 7;
    qv[xi] = bf2f(smem[row*64 + ((chunk ^ (row & 7))*8) + e]);
  }

  __syncthreads();
  float* fa = (float*)smem;
#pragma unroll
  for (int fj=0; fj<4; fj++)
#pragma unroll
    for (int r=0; r<4; r++)
      fa[(w*16 + lg*4 + r)*64 + fj*16 + lr] = 0.125f * fac[fj][r];
  __syncthreads();

#pragma unroll
  for (int xi=0; xi<14; xi++){
    int nn = n0 + x0 + xi;
    out_pre[((size_t)b*NTOK + nn)*CDIM + h*64 + d] =
        f2bf(fa[(x0 + xi)*64 + d] + creg[xi]*qv[xi]);
  }
}

// ---------------- K4: n=0 row: out = scale * q[0] @ kvT^T ----------------
__global__ void fa0_kernel(const u16* __restrict__ q_s, const u16* __restrict__ kvT,
                           u16* __restrict__ out_pre){
  const int b = blockIdx.x, t = threadIdx.x;   // 512 threads
  const int h = t >> 6, d = t & 63;
  const int bh = b*8 + h;
  float s = 0.f;
#pragma unroll
  for (int k=0; k<64; k++)
    s += bf2f(q_s[(size_t)bh*NTOK*64 + k]) * bf2f(kvT[(size_t)bh*4096 + d*64 + k]);
  out_pre[(size_t)b*NTOK*CDIM + h*64 + d] = f2bf(0.125f * s);
}

extern "C" void kernel_launch(void* const* d_in, const int* in_sizes, int n_in,
                              void* d_out, int out_size, void* d_ws, size_t ws_size,
                              hipStream_t stream)
{
  const float* x      = (const float*)d_in[0];
  const float* qkv_w  = (const float*)d_in[1];
  const float* qkv_b  = (const float*)d_in[2];
  const float* proj_w = (const float*)d_in[3];
  const float* proj_b = (const float*)d_in[4];
  const float* w3 = (const float*)d_in[5];
  const float* b3 = (const float*)d_in[6];
  const float* w5 = (const float*)d_in[7];
  const float* b5 = (const float*)d_in[8];
  const float* w7 = (const float*)d_in[9];
  const float* b7 = (const float*)d_in[10];
  float* out = (float*)d_out;

  char* ws = (char*)d_ws;
  size_t off = 0;
  auto alloc = [&](size_t bytes) -> void* {
    void* p = ws + off;
    off += (bytes + 255) & ~(size_t)255;
    return p;
  };
  u16*   x_bf     = (u16*)alloc((size_t)MT*512*2);        // reused as out_pre after qkv GEMM
  u16*   qkvw_bf  = (u16*)alloc((size_t)1536*512*2);
  u16*   projw_bf = (u16*)alloc((size_t)512*512*2);
  u16*   q_s      = (u16*)alloc((size_t)128*NTOK*64*2);
  u16*   k_s      = (u16*)alloc((size_t)128*NTOK*64*2);
  u16*   v_s      = (u16*)alloc((size_t)128*NTOK*64*2);
  u16*   kvT      = (u16*)alloc((size_t)128*4096*2);
  float* kv_p     = (float*)alloc((size_t)4*128*4096*4);
  float* s_p      = (float*)alloc((size_t)4*128*64*4);
  u16*   out_pre  = x_bf;

  { int n4 = (MT*512)/4;   cvt_kernel<<<(n4+255)/256, 256, 0, stream>>>(x, x_bf, n4); }
  { int n4 = (1536*512)/4; cvt_kernel<<<(n4+255)/256, 256, 0, stream>>>(qkv_w, qkvw_bf, n4); }
  { int n4 = (512*512)/4;  cvt_kernel<<<(n4+255)/256, 256, 0, stream>>>(proj_w, projw_bf, n4); }

  // qkv: M=50192, N=1536, K=512 — 256x256 2-phase, counted vmcnt
  gemm2<256,256,2,4,0><<<dim3(6, 197), 512, 0, stream>>>(
      x_bf, qkvw_bf, qkv_b, q_s, k_s, v_s, nullptr, MT);

  kv_partial<<<dim3(128, 4), 256, 0, stream>>>(k_s, v_s, kv_p, s_p);
  kv_reduce<<<128, 256, 0, stream>>>(kv_p, s_p, kvT);
  fa0_kernel<<<16, 512, 0, stream>>>(q_s, kvT, out_pre);

  conv_fa<1><<<dim3(56, 2, 16), 256, 0, stream>>>(v_s, q_s, kvT, w3, b3, 0, out_pre);
  conv_fa<2><<<dim3(56, 3, 16), 256, 0, stream>>>(v_s, q_s, kvT, w5, b5, 2, out_pre);
  conv_fa<3><<<dim3(56, 3, 16), 256, 0, stream>>>(v_s, q_s, kvT, w7, b7, 5, out_pre);

  // proj: M=50192, N=512, K=512 — 128x128 2-phase, counted vmcnt
  gemm2<128,128,2,2,1><<<dim3(4, 393), 256, 0, stream>>>(
      out_pre, projw_bf, proj_b, nullptr, nullptr, nullptr, out, MT);
}